// Round 9
// baseline (211.032 us; speedup 1.0000x reference)
//
#include <hip/hip_runtime.h>
#include <hip/hip_bf16.h>
#include <math.h>

#define LEAKY(x) ((x) >= 0.0f ? (x) : 0.2f * (x))
#define CHUNK 8192

typedef __attribute__((ext_vector_type(8))) short short8;
typedef __attribute__((ext_vector_type(4))) float f32x4;

__device__ __forceinline__ float bf_lo(uint32_t u) { return __uint_as_float(u << 16); }
__device__ __forceinline__ float bf_hi(uint32_t u) { return __uint_as_float(u & 0xffff0000u); }
__device__ __forceinline__ uint32_t pack2(float a, float b) {
    __hip_bfloat162 h = __float22bfloat162_rn(make_float2(a, b));
    return *reinterpret_cast<uint32_t*>(&h);
}

// ---------------------------------------------------------------------------
// w_prep: pack W (f32 [128 k][128 col]) into bf16 MFMA B-fragment order.
// ---------------------------------------------------------------------------
__global__ __launch_bounds__(256) void w_prep(
    const float* __restrict__ W, uint32_t* __restrict__ Wp)
{
    const int slot = blockIdx.x * 256 + threadIdx.x;
    if (slot >= 2048) return;
    const int kb = slot >> 9;
    const int cb = (slot >> 6) & 7;
    const int l  = slot & 63;
    const int k0 = kb * 32 + (l >> 4) * 8;
    const int col = cb * 16 + (l & 15);
    uint32_t u[4];
    #pragma unroll
    for (int p = 0; p < 4; ++p) {
        const float a = W[(size_t)(k0 + 2 * p) * 128 + col];
        const float b = W[(size_t)(k0 + 2 * p + 1) * 128 + col];
        u[p] = pack2(a, b);
    }
    *(uint4*)&Wp[(size_t)slot * 4] = make_uint4(u[0], u[1], u[2], u[3]);
}

// ---------------------------------------------------------------------------
// gemm: MFMA xp = bf16(x @ W) + attn_self/attn_neigh. 64 nodes/block.
// ---------------------------------------------------------------------------
__global__ __launch_bounds__(256) void gemm_xp(
    const float* __restrict__ x, const uint32_t* __restrict__ Wp,
    const float* __restrict__ aks, const float* __restrict__ akn,
    uint32_t* __restrict__ xpb, float* __restrict__ attn_self,
    float* __restrict__ attn_nei, int N)
{
    __shared__ float xs[64][133];
    const int t  = threadIdx.x;
    const int w  = t >> 6;
    const int l  = t & 63;
    const int nb = blockIdx.x * 64;

    const int row  = nb + w * 16 + (l & 15);
    const int rowc = min(row, N - 1);
    const int kg   = (l >> 4) * 8;
    const float* xrow = x + (size_t)rowc * 128 + kg;

    f32x4 acc[8] = {};
    #pragma unroll
    for (int kb = 0; kb < 4; ++kb) {
        const float4 x0 = *(const float4*)(xrow + kb * 32);
        const float4 x1 = *(const float4*)(xrow + kb * 32 + 4);
        union { short8 s; uint32_t u[4]; } A;
        A.u[0] = pack2(x0.x, x0.y); A.u[1] = pack2(x0.z, x0.w);
        A.u[2] = pack2(x1.x, x1.y); A.u[3] = pack2(x1.z, x1.w);
        #pragma unroll
        for (int cb = 0; cb < 8; ++cb) {
            union { short8 s; uint4 u; } B;
            B.u = *(const uint4*)&Wp[(((size_t)(kb * 8 + cb)) * 64 + l) * 4];
            acc[cb] = __builtin_amdgcn_mfma_f32_16x16x32_bf16(A.s, B.s, acc[cb], 0, 0, 0);
        }
    }

    const int r0 = (l >> 4) * 4;
    const int cl = l & 15;
    #pragma unroll
    for (int cb = 0; cb < 8; ++cb)
        #pragma unroll
        for (int r = 0; r < 4; ++r)
            xs[w * 16 + r0 + r][cb * 16 + cl] = acc[cb][r];
    __syncthreads();

    #pragma unroll
    for (int i = 0; i < 16; ++i) {
        const int idx = t + i * 256;           // 0..4095
        const int n = idx >> 6, q = idx & 63;
        const int gn = nb + n;
        if (gn < N)
            xpb[(size_t)gn * 64 + q] = pack2(xs[n][2 * q], xs[n][2 * q + 1]);
    }

    {
        const int n = t & 63, h = t >> 6;
        const int gn = nb + n;
        if (gn < N) {
            float ss = 0.0f, sn = 0.0f;
            #pragma unroll
            for (int c = 0; c < 32; ++c) {
                const float v = xs[n][h * 32 + c];
                ss = fmaf(v, aks[c * 4 + h], ss);
                sn = fmaf(v, akn[c * 4 + h], sn);
            }
            attn_self[(size_t)gn * 4 + h] = ss;
            attn_nei [(size_t)gn * 4 + h] = sn;
        }
    }
}

// ---------------------------------------------------------------------------
// binA: per-chunk bucket binning (bucket = tgt>>8), LDS hist/scan, pairs into
// the chunk's own stage region + start_table + bucket totals.
// ---------------------------------------------------------------------------
__global__ __launch_bounds__(256) void binA(
    const int* __restrict__ ei, int2* __restrict__ stage,
    int* __restrict__ start_table, int* __restrict__ bucket_tot,
    int NB, int E)
{
    __shared__ int lh[512], lex[512], ss[256];
    const int t    = threadIdx.x;
    const int base = blockIdx.x * CHUNK;
    const int end  = min(E, base + CHUNK);

    for (int i = t; i < 512; i += 256) lh[i] = 0;
    __syncthreads();
    for (int i = base + t; i < end; i += 256)
        atomicAdd(&lh[((const int2*)ei)[i].y >> 8], 1);
    __syncthreads();

    const int v0 = lh[2 * t], v1 = lh[2 * t + 1];
    ss[t] = v0 + v1;
    __syncthreads();
    for (int d = 1; d < 256; d <<= 1) {
        const int add = (t >= d) ? ss[t - d] : 0;
        __syncthreads();
        ss[t] += add;
        __syncthreads();
    }
    const int ex = ss[t] - v0 - v1;
    lex[2 * t] = ex;
    lex[2 * t + 1] = ex + v0;
    __syncthreads();

    const size_t cbase = (size_t)blockIdx.x * (NB + 1);
    for (int b = t; b <= NB; b += 256) start_table[cbase + b] = base + lex[b];
    for (int b = t; b < NB; b += 256)
        if (lh[b]) atomicAdd(&bucket_tot[b], lh[b]);
    __syncthreads();

    for (int i = base + t; i < end; i += 256) {
        const int2 e2 = ((const int2*)ei)[i];
        const int slot = atomicAdd(&lex[e2.y >> 8], 1);
        stage[base + slot] = e2;
    }
}

// ---------------------------------------------------------------------------
// bucket_scan: 1 block; exclusive scan of bucket totals; offsets[N] = E.
// ---------------------------------------------------------------------------
__global__ __launch_bounds__(256) void bucket_scan(
    const int* __restrict__ bucket_tot, int* __restrict__ bucket_off,
    int* __restrict__ offsets, int NB, int N, int E)
{
    __shared__ int ss[256];
    const int t = threadIdx.x;
    const int v0 = (2 * t     < NB) ? bucket_tot[2 * t]     : 0;
    const int v1 = (2 * t + 1 < NB) ? bucket_tot[2 * t + 1] : 0;
    ss[t] = v0 + v1;
    __syncthreads();
    for (int d = 1; d < 256; d <<= 1) {
        const int add = (t >= d) ? ss[t - d] : 0;
        __syncthreads();
        ss[t] += add;
        __syncthreads();
    }
    const int ex = ss[t] - v0 - v1;
    if (2 * t     <= NB) bucket_off[2 * t]     = ex;
    if (2 * t + 1 <= NB) bucket_off[2 * t + 1] = ex + v0;
    if (t == 0) offsets[N] = E;
}

// ---------------------------------------------------------------------------
// binB: one block per bucket; per-node counts/scan/scatter in LDS; writes
// offsets[lo..hi) and csr_src with single-block write locality.
// ---------------------------------------------------------------------------
__global__ __launch_bounds__(256) void binB(
    const int2* __restrict__ stage, const int* __restrict__ start_table,
    const int* __restrict__ bucket_off, int* __restrict__ offsets,
    int* __restrict__ csr_src, int nc, int NB, int N)
{
    __shared__ int s0[256], cum[257], ss[256], lcnt[256], lcur[256];
    const int t  = threadIdx.x;
    const int b  = blockIdx.x;
    const int lo = b << 8;
    const int nn = min(N, lo + 256) - lo;

    int len = 0;
    if (t < nc) {
        const size_t cb = (size_t)t * (NB + 1);
        const int a0 = start_table[cb + b];
        s0[t] = a0;
        len   = start_table[cb + b + 1] - a0;
    }
    ss[t] = len;
    lcnt[t] = 0;
    __syncthreads();
    for (int d = 1; d < 256; d <<= 1) {
        const int add = (t >= d) ? ss[t - d] : 0;
        __syncthreads();
        ss[t] += add;
        __syncthreads();
    }
    if (t == 0) cum[0] = 0;
    cum[t + 1] = ss[t];
    __syncthreads();
    const int T = cum[nc];

    for (int g = t; g < T; g += 256) {
        int loc = 0, hic = nc - 1;
        while (loc < hic) {
            const int mid = (loc + hic + 1) >> 1;
            if (cum[mid] <= g) loc = mid; else hic = mid - 1;
        }
        const int2 e = stage[s0[loc] + (g - cum[loc])];
        atomicAdd(&lcnt[e.y - lo], 1);
    }
    __syncthreads();

    const int v = lcnt[t];
    ss[t] = v;
    __syncthreads();
    for (int d = 1; d < 256; d <<= 1) {
        const int add = (t >= d) ? ss[t - d] : 0;
        __syncthreads();
        ss[t] += add;
        __syncthreads();
    }
    const int nodeoff = bucket_off[b] + ss[t] - v;
    lcur[t] = nodeoff;
    if (t < nn) offsets[lo + t] = nodeoff;
    __syncthreads();

    for (int g = t; g < T; g += 256) {
        int loc = 0, hic = nc - 1;
        while (loc < hic) {
            const int mid = (loc + hic + 1) >> 1;
            if (cum[mid] <= g) loc = mid; else hic = mid - 1;
        }
        const int2 e = stage[s0[loc] + (g - cum[loc])];
        const int slot = atomicAdd(&lcur[e.y - lo], 1);
        csr_src[slot] = e.x;
    }
}

// ---------------------------------------------------------------------------
// aggregate v3: one wave per node; 4 edge-groups x 16 lanes. Each group
// gathers its edge's full 256 B xpb row as dwordx4 (16 B/lane); exp computed
// by 16 lanes (not 64); cross-group shfl reduce at the end.
// ---------------------------------------------------------------------------
__global__ __launch_bounds__(256) void aggregate(
    const int* __restrict__ csr_src, const int* __restrict__ offsets,
    const uint32_t* __restrict__ xpb, const float* __restrict__ attn_self,
    const float* __restrict__ attn_nei, const float* __restrict__ bias,
    float* __restrict__ out, float* __restrict__ alpha_out,
    float* __restrict__ inv_arr, int N, int E)
{
    const int lane = threadIdx.x & 63;
    int node = blockIdx.x * 4 + (threadIdx.x >> 6);
    if (node >= N) return;
    node = __builtin_amdgcn_readfirstlane(node);

    const int g  = lane >> 4;         // edge group 0..3
    const int li = lane & 15;         // lane in group
    const int hL = li >> 2;           // head of this lane's 8 channels
    const int q0 = li * 4;            // first uint32 of the row (16 B/lane)

    const float asH = attn_self[(size_t)node * 4 + hL];
    const float anH = attn_nei [(size_t)node * 4 + hL];
    const float eS  = __expf(LEAKY(asH + anH));

    const float es0 = (g == 0) ? eS : 0.0f;   // self term in group 0 only
    const uint4 uS = *(const uint4*)&xpb[(size_t)node * 64 + q0];
    float acc[8];
    acc[0] = es0 * bf_lo(uS.x); acc[1] = es0 * bf_hi(uS.x);
    acc[2] = es0 * bf_lo(uS.y); acc[3] = es0 * bf_hi(uS.y);
    acc[4] = es0 * bf_lo(uS.z); acc[5] = es0 * bf_hi(uS.z);
    acc[6] = es0 * bf_lo(uS.w); acc[7] = es0 * bf_hi(uS.w);
    float sumE = es0;

    const int off0 = __builtin_amdgcn_readfirstlane(offsets[node]);
    const int deg  = __builtin_amdgcn_readfirstlane(offsets[node + 1]) - off0;
    const int* srcp = csr_src + off0;

    for (int j = 0; j < deg; j += 4) {
        const int e   = j + g;
        const int idx = min(e, deg - 1);
        const int s   = srcp[idx];
        const float an = attn_nei[(size_t)s * 4 + hL];
        const uint4 u  = *(const uint4*)&xpb[(size_t)s * 64 + q0];
        const float v  = (e < deg) ? __expf(LEAKY(asH + an)) : 0.0f;
        sumE += v;
        acc[0] = fmaf(v, bf_lo(u.x), acc[0]); acc[1] = fmaf(v, bf_hi(u.x), acc[1]);
        acc[2] = fmaf(v, bf_lo(u.y), acc[2]); acc[3] = fmaf(v, bf_hi(u.y), acc[3]);
        acc[4] = fmaf(v, bf_lo(u.z), acc[4]); acc[5] = fmaf(v, bf_hi(u.z), acc[5]);
        acc[6] = fmaf(v, bf_lo(u.w), acc[6]); acc[7] = fmaf(v, bf_hi(u.w), acc[7]);
    }

    // cross-group reduce (lanes with equal li)
    #pragma unroll
    for (int d = 16; d < 64; d <<= 1) {
        sumE += __shfl_xor(sumE, d);
        #pragma unroll
        for (int k = 0; k < 8; ++k) acc[k] += __shfl_xor(acc[k], d);
    }

    const float inv = 1.0f / sumE;
    if (g == 0) {
        const int c0 = li * 8;
        float4 o0, o1;
        o0.x = fmaf(acc[0], inv, bias[c0 + 0]);
        o0.y = fmaf(acc[1], inv, bias[c0 + 1]);
        o0.z = fmaf(acc[2], inv, bias[c0 + 2]);
        o0.w = fmaf(acc[3], inv, bias[c0 + 3]);
        o1.x = fmaf(acc[4], inv, bias[c0 + 4]);
        o1.y = fmaf(acc[5], inv, bias[c0 + 5]);
        o1.z = fmaf(acc[6], inv, bias[c0 + 6]);
        o1.w = fmaf(acc[7], inv, bias[c0 + 7]);
        *(float4*)&out[(size_t)node * 128 + c0]     = o0;
        *(float4*)&out[(size_t)node * 128 + c0 + 4] = o1;
        if ((li & 3) == 0) {
            inv_arr[(size_t)node * 4 + hL] = inv;
            alpha_out[(size_t)(E + node) * 4 + hL] = eS * inv;
        }
    }
}

// ---------------------------------------------------------------------------
// alpha for the E real edges, coalesced by edge id (overwrites stage scratch).
// ---------------------------------------------------------------------------
__global__ __launch_bounds__(256) void alpha_kernel(
    const int* __restrict__ ei, const float* __restrict__ attn_self,
    const float* __restrict__ attn_nei, const float* __restrict__ inv_arr,
    float* __restrict__ alpha_out, int E)
{
    const int i = blockIdx.x * 256 + threadIdx.x;
    if (i >= E) return;
    const int2 e2 = ((const int2*)ei)[i];
    const int src = e2.x, tgt = e2.y;
    const float4 as4 = *(const float4*)&attn_self[(size_t)tgt * 4];
    const float4 an4 = *(const float4*)&attn_nei[(size_t)src * 4];
    const float4 iv4 = *(const float4*)&inv_arr[(size_t)tgt * 4];
    float4 a;
    a.x = __expf(LEAKY(as4.x + an4.x)) * iv4.x;
    a.y = __expf(LEAKY(as4.y + an4.y)) * iv4.y;
    a.z = __expf(LEAKY(as4.z + an4.z)) * iv4.z;
    a.w = __expf(LEAKY(as4.w + an4.w)) * iv4.w;
    *(float4*)&alpha_out[(size_t)i * 4] = a;
}

// ---------------------------------------------------------------------------
extern "C" void kernel_launch(void* const* d_in, const int* in_sizes, int n_in,
                              void* d_out, int out_size, void* d_ws, size_t ws_size,
                              hipStream_t stream)
{
    const float* x    = (const float*)d_in[0];
    const int*   ei   = (const int*)d_in[1];
    const float* W    = (const float*)d_in[2];
    const float* aks  = (const float*)d_in[3];
    const float* akn  = (const float*)d_in[4];
    const float* bias = (const float*)d_in[5];

    const int N  = in_sizes[0] / 128;
    const int E  = in_sizes[1] / 2;
    const int NB = (N + 255) >> 8;
    const int nc = (E + CHUNK - 1) / CHUNK;

    float* out       = (float*)d_out;
    float* alpha_out = out + (size_t)N * 128;
    int2* stage      = (int2*)alpha_out;   // overlays alpha region (see r7 note)

    char* p = (char*)d_ws;
    auto alloc = [&](size_t bytes) {
        char* r = p;
        p += (bytes + 255) & ~(size_t)255;
        return r;
    };
    uint32_t* xpb       = (uint32_t*)alloc((size_t)N * 64 * 4);
    uint32_t* Wp        = (uint32_t*)alloc((size_t)2048 * 16);
    float* attn_self    = (float*)alloc((size_t)N * 4 * 4);
    float* attn_nei     = (float*)alloc((size_t)N * 4 * 4);
    float* inv_arr      = (float*)alloc((size_t)N * 4 * 4);
    int*   offsets      = (int*)alloc((size_t)(N + 1) * 4);
    int*   csr_src      = (int*)alloc((size_t)E * 4);
    int*   bucket_tot   = (int*)alloc((size_t)NB * 4);
    int*   bucket_off   = (int*)alloc((size_t)(NB + 1) * 4);
    int*   start_table  = (int*)alloc((size_t)nc * (NB + 1) * 4);

    hipMemsetAsync(bucket_tot, 0, (size_t)NB * 4, stream);

    w_prep<<<8, 256, 0, stream>>>(W, Wp);
    gemm_xp<<<(N + 63) / 64, 256, 0, stream>>>(x, Wp, aks, akn, xpb,
                                               attn_self, attn_nei, N);
    binA<<<nc, 256, 0, stream>>>(ei, stage, start_table, bucket_tot, NB, E);
    bucket_scan<<<1, 256, 0, stream>>>(bucket_tot, bucket_off, offsets, NB, N, E);
    binB<<<NB, 256, 0, stream>>>(stage, start_table, bucket_off, offsets,
                                 csr_src, nc, NB, N);
    aggregate<<<(N + 3) / 4, 256, 0, stream>>>(csr_src, offsets, xpb,
                                               attn_self, attn_nei, bias, out,
                                               alpha_out, inv_arr, N, E);
    alpha_kernel<<<(E + 255) / 256, 256, 0, stream>>>(ei, attn_self, attn_nei,
                                                      inv_arr, alpha_out, E);
}

// Round 10
// 207.964 us; speedup vs baseline: 1.0148x; 1.0148x over previous
//
#include <hip/hip_runtime.h>
#include <hip/hip_bf16.h>
#include <math.h>

#define LEAKY(x) ((x) >= 0.0f ? (x) : 0.2f * (x))
#define CHUNK 8192

typedef __attribute__((ext_vector_type(8))) short short8;
typedef __attribute__((ext_vector_type(4))) float f32x4;
typedef __attribute__((ext_vector_type(2))) int i32x2;

__device__ __forceinline__ float bf_lo(uint32_t u) { return __uint_as_float(u << 16); }
__device__ __forceinline__ float bf_hi(uint32_t u) { return __uint_as_float(u & 0xffff0000u); }
__device__ __forceinline__ uint32_t pack2(float a, float b) {
    __hip_bfloat162 h = __float22bfloat162_rn(make_float2(a, b));
    return *reinterpret_cast<uint32_t*>(&h);
}

// ---------------------------------------------------------------------------
// w_prep: pack W (f32 [128 k][128 col]) into bf16 MFMA B-fragment order.
// ---------------------------------------------------------------------------
__global__ __launch_bounds__(256) void w_prep(
    const float* __restrict__ W, uint32_t* __restrict__ Wp)
{
    const int slot = blockIdx.x * 256 + threadIdx.x;
    if (slot >= 2048) return;
    const int kb = slot >> 9;
    const int cb = (slot >> 6) & 7;
    const int l  = slot & 63;
    const int k0 = kb * 32 + (l >> 4) * 8;
    const int col = cb * 16 + (l & 15);
    uint32_t u[4];
    #pragma unroll
    for (int p = 0; p < 4; ++p) {
        const float a = W[(size_t)(k0 + 2 * p) * 128 + col];
        const float b = W[(size_t)(k0 + 2 * p + 1) * 128 + col];
        u[p] = pack2(a, b);
    }
    *(uint4*)&Wp[(size_t)slot * 4] = make_uint4(u[0], u[1], u[2], u[3]);
}

// ---------------------------------------------------------------------------
// gemm: MFMA xp = bf16(x @ W) + attn_self/attn_neigh. 64 nodes/block.
// ---------------------------------------------------------------------------
__global__ __launch_bounds__(256) void gemm_xp(
    const float* __restrict__ x, const uint32_t* __restrict__ Wp,
    const float* __restrict__ aks, const float* __restrict__ akn,
    uint32_t* __restrict__ xpb, float* __restrict__ attn_self,
    float* __restrict__ attn_nei, int N)
{
    __shared__ float xs[64][133];
    const int t  = threadIdx.x;
    const int w  = t >> 6;
    const int l  = t & 63;
    const int nb = blockIdx.x * 64;

    const int row  = nb + w * 16 + (l & 15);
    const int rowc = min(row, N - 1);
    const int kg   = (l >> 4) * 8;
    const float* xrow = x + (size_t)rowc * 128 + kg;

    f32x4 acc[8] = {};
    #pragma unroll
    for (int kb = 0; kb < 4; ++kb) {
        const float4 x0 = *(const float4*)(xrow + kb * 32);
        const float4 x1 = *(const float4*)(xrow + kb * 32 + 4);
        union { short8 s; uint32_t u[4]; } A;
        A.u[0] = pack2(x0.x, x0.y); A.u[1] = pack2(x0.z, x0.w);
        A.u[2] = pack2(x1.x, x1.y); A.u[3] = pack2(x1.z, x1.w);
        #pragma unroll
        for (int cb = 0; cb < 8; ++cb) {
            union { short8 s; uint4 u; } B;
            B.u = *(const uint4*)&Wp[(((size_t)(kb * 8 + cb)) * 64 + l) * 4];
            acc[cb] = __builtin_amdgcn_mfma_f32_16x16x32_bf16(A.s, B.s, acc[cb], 0, 0, 0);
        }
    }

    const int r0 = (l >> 4) * 4;
    const int cl = l & 15;
    #pragma unroll
    for (int cb = 0; cb < 8; ++cb)
        #pragma unroll
        for (int r = 0; r < 4; ++r)
            xs[w * 16 + r0 + r][cb * 16 + cl] = acc[cb][r];
    __syncthreads();

    #pragma unroll
    for (int i = 0; i < 16; ++i) {
        const int idx = t + i * 256;           // 0..4095
        const int n = idx >> 6, q = idx & 63;
        const int gn = nb + n;
        if (gn < N)
            xpb[(size_t)gn * 64 + q] = pack2(xs[n][2 * q], xs[n][2 * q + 1]);
    }

    {
        const int n = t & 63, h = t >> 6;
        const int gn = nb + n;
        if (gn < N) {
            float ss = 0.0f, sn = 0.0f;
            #pragma unroll
            for (int c = 0; c < 32; ++c) {
                const float v = xs[n][h * 32 + c];
                ss = fmaf(v, aks[c * 4 + h], ss);
                sn = fmaf(v, akn[c * 4 + h], sn);
            }
            attn_self[(size_t)gn * 4 + h] = ss;
            attn_nei [(size_t)gn * 4 + h] = sn;
        }
    }
}

// ---------------------------------------------------------------------------
// binA: per-chunk bucket binning (bucket = tgt>>8), LDS hist/scan, pairs into
// the chunk's own stage region + start_table + bucket totals.
// ---------------------------------------------------------------------------
__global__ __launch_bounds__(256) void binA(
    const int* __restrict__ ei, int2* __restrict__ stage,
    int* __restrict__ start_table, int* __restrict__ bucket_tot,
    int NB, int E)
{
    __shared__ int lh[512], lex[512], ss[256];
    const int t    = threadIdx.x;
    const int base = blockIdx.x * CHUNK;
    const int end  = min(E, base + CHUNK);

    for (int i = t; i < 512; i += 256) lh[i] = 0;
    __syncthreads();
    for (int i = base + t; i < end; i += 256)
        atomicAdd(&lh[((const int2*)ei)[i].y >> 8], 1);
    __syncthreads();

    const int v0 = lh[2 * t], v1 = lh[2 * t + 1];
    ss[t] = v0 + v1;
    __syncthreads();
    for (int d = 1; d < 256; d <<= 1) {
        const int add = (t >= d) ? ss[t - d] : 0;
        __syncthreads();
        ss[t] += add;
        __syncthreads();
    }
    const int ex = ss[t] - v0 - v1;
    lex[2 * t] = ex;
    lex[2 * t + 1] = ex + v0;
    __syncthreads();

    const size_t cbase = (size_t)blockIdx.x * (NB + 1);
    for (int b = t; b <= NB; b += 256) start_table[cbase + b] = base + lex[b];
    for (int b = t; b < NB; b += 256)
        if (lh[b]) atomicAdd(&bucket_tot[b], lh[b]);
    __syncthreads();

    for (int i = base + t; i < end; i += 256) {
        const int2 e2 = ((const int2*)ei)[i];
        const int slot = atomicAdd(&lex[e2.y >> 8], 1);
        stage[base + slot] = e2;
    }
}

// ---------------------------------------------------------------------------
// bucket_scan: 1 block; exclusive scan of bucket totals; offsets[N] = E.
// ---------------------------------------------------------------------------
__global__ __launch_bounds__(256) void bucket_scan(
    const int* __restrict__ bucket_tot, int* __restrict__ bucket_off,
    int* __restrict__ offsets, int NB, int N, int E)
{
    __shared__ int ss[256];
    const int t = threadIdx.x;
    const int v0 = (2 * t     < NB) ? bucket_tot[2 * t]     : 0;
    const int v1 = (2 * t + 1 < NB) ? bucket_tot[2 * t + 1] : 0;
    ss[t] = v0 + v1;
    __syncthreads();
    for (int d = 1; d < 256; d <<= 1) {
        const int add = (t >= d) ? ss[t - d] : 0;
        __syncthreads();
        ss[t] += add;
        __syncthreads();
    }
    const int ex = ss[t] - v0 - v1;
    if (2 * t     <= NB) bucket_off[2 * t]     = ex;
    if (2 * t + 1 <= NB) bucket_off[2 * t + 1] = ex + v0;
    if (t == 0) offsets[N] = E;
}

// ---------------------------------------------------------------------------
// binB: one block per bucket; per-node counts/scan/scatter in LDS; writes
// offsets[lo..hi) and csr_src with single-block write locality.
// ---------------------------------------------------------------------------
__global__ __launch_bounds__(256) void binB(
    const int2* __restrict__ stage, const int* __restrict__ start_table,
    const int* __restrict__ bucket_off, int* __restrict__ offsets,
    int* __restrict__ csr_src, int nc, int NB, int N)
{
    __shared__ int s0[256], cum[257], ss[256], lcnt[256], lcur[256];
    const int t  = threadIdx.x;
    const int b  = blockIdx.x;
    const int lo = b << 8;
    const int nn = min(N, lo + 256) - lo;

    int len = 0;
    if (t < nc) {
        const size_t cb = (size_t)t * (NB + 1);
        const int a0 = start_table[cb + b];
        s0[t] = a0;
        len   = start_table[cb + b + 1] - a0;
    }
    ss[t] = len;
    lcnt[t] = 0;
    __syncthreads();
    for (int d = 1; d < 256; d <<= 1) {
        const int add = (t >= d) ? ss[t - d] : 0;
        __syncthreads();
        ss[t] += add;
        __syncthreads();
    }
    if (t == 0) cum[0] = 0;
    cum[t + 1] = ss[t];
    __syncthreads();
    const int T = cum[nc];

    for (int g = t; g < T; g += 256) {
        int loc = 0, hic = nc - 1;
        while (loc < hic) {
            const int mid = (loc + hic + 1) >> 1;
            if (cum[mid] <= g) loc = mid; else hic = mid - 1;
        }
        const int2 e = stage[s0[loc] + (g - cum[loc])];
        atomicAdd(&lcnt[e.y - lo], 1);
    }
    __syncthreads();

    const int v = lcnt[t];
    ss[t] = v;
    __syncthreads();
    for (int d = 1; d < 256; d <<= 1) {
        const int add = (t >= d) ? ss[t - d] : 0;
        __syncthreads();
        ss[t] += add;
        __syncthreads();
    }
    const int nodeoff = bucket_off[b] + ss[t] - v;
    lcur[t] = nodeoff;
    if (t < nn) offsets[lo + t] = nodeoff;
    __syncthreads();

    for (int g = t; g < T; g += 256) {
        int loc = 0, hic = nc - 1;
        while (loc < hic) {
            const int mid = (loc + hic + 1) >> 1;
            if (cum[mid] <= g) loc = mid; else hic = mid - 1;
        }
        const int2 e = stage[s0[loc] + (g - cum[loc])];
        const int slot = atomicAdd(&lcur[e.y - lo], 1);
        csr_src[slot] = e.x;
    }
}

// ---------------------------------------------------------------------------
// aggregate v4: round-8 structure (one wave/node, lane = 2 channels),
// unroll 8 for more gathers in flight, NON-TEMPORAL out stores so the 51 MB
// result stream doesn't evict xpb from L3.
// ---------------------------------------------------------------------------
__global__ __launch_bounds__(256) void aggregate(
    const int* __restrict__ csr_src, const int* __restrict__ offsets,
    const uint32_t* __restrict__ xpb, const float* __restrict__ attn_self,
    const float* __restrict__ attn_nei, const float* __restrict__ bias,
    float* __restrict__ out, float* __restrict__ alpha_out,
    float* __restrict__ inv_arr, int N, int E)
{
    const int lane = threadIdx.x & 63;
    int node = blockIdx.x * 4 + (threadIdx.x >> 6);
    if (node >= N) return;
    node = __builtin_amdgcn_readfirstlane(node);

    const int hL = lane >> 4;        // head of this lane's 2 channels
    const int c0 = 2 * lane;

    const float asH = attn_self[(size_t)node * 4 + hL];
    const float anH = attn_nei [(size_t)node * 4 + hL];
    const float eS  = __expf(LEAKY(asH + anH));
    float sumE = eS;
    const uint32_t uS = xpb[(size_t)node * 64 + lane];
    float acc0 = eS * bf_lo(uS), acc1 = eS * bf_hi(uS);

    const int off0 = __builtin_amdgcn_readfirstlane(offsets[node]);
    const int deg  = __builtin_amdgcn_readfirstlane(offsets[node + 1]) - off0;
    const int* srcp = csr_src + off0;

    for (int j = 0; j < deg; j += 8) {
        int s[8];
        #pragma unroll
        for (int k = 0; k < 8; ++k) s[k] = srcp[min(j + k, deg - 1)];
        float a[8];
        #pragma unroll
        for (int k = 0; k < 8; ++k) a[k] = attn_nei[(size_t)s[k] * 4 + hL];
        uint32_t u[8];
        #pragma unroll
        for (int k = 0; k < 8; ++k) u[k] = xpb[(size_t)s[k] * 64 + lane];
        #pragma unroll
        for (int k = 0; k < 8; ++k) {
            const float v = (j + k < deg) ? __expf(LEAKY(asH + a[k])) : 0.0f;
            sumE += v;
            acc0 = fmaf(v, bf_lo(u[k]), acc0);
            acc1 = fmaf(v, bf_hi(u[k]), acc1);
        }
    }

    const float inv = 1.0f / sumE;
    union { float2 f; unsigned long long u; } o;
    o.f = make_float2(fmaf(acc0, inv, bias[c0]), fmaf(acc1, inv, bias[c0 + 1]));
    __builtin_nontemporal_store(o.u,
        (unsigned long long*)&out[(size_t)node * 128 + c0]);
    if ((lane & 15) == 0) {
        inv_arr[(size_t)node * 4 + hL] = inv;
        __builtin_nontemporal_store(eS * inv,
            &alpha_out[(size_t)(E + node) * 4 + hL]);
    }
}

// ---------------------------------------------------------------------------
// alpha for the E real edges: nt ei loads + nt alpha stores (pure stream,
// never re-read — keep it out of L3).
// ---------------------------------------------------------------------------
__global__ __launch_bounds__(256) void alpha_kernel(
    const int* __restrict__ ei, const float* __restrict__ attn_self,
    const float* __restrict__ attn_nei, const float* __restrict__ inv_arr,
    float* __restrict__ alpha_out, int E)
{
    const int i = blockIdx.x * 256 + threadIdx.x;
    if (i >= E) return;
    const i32x2 e2 = __builtin_nontemporal_load((const i32x2*)ei + i);
    const int src = e2.x, tgt = e2.y;
    const float4 as4 = *(const float4*)&attn_self[(size_t)tgt * 4];
    const float4 an4 = *(const float4*)&attn_nei[(size_t)src * 4];
    const float4 iv4 = *(const float4*)&inv_arr[(size_t)tgt * 4];
    f32x4 a;
    a.x = __expf(LEAKY(as4.x + an4.x)) * iv4.x;
    a.y = __expf(LEAKY(as4.y + an4.y)) * iv4.y;
    a.z = __expf(LEAKY(as4.z + an4.z)) * iv4.z;
    a.w = __expf(LEAKY(as4.w + an4.w)) * iv4.w;
    __builtin_nontemporal_store(a, (f32x4*)&alpha_out[(size_t)i * 4]);
}

// ---------------------------------------------------------------------------
extern "C" void kernel_launch(void* const* d_in, const int* in_sizes, int n_in,
                              void* d_out, int out_size, void* d_ws, size_t ws_size,
                              hipStream_t stream)
{
    const float* x    = (const float*)d_in[0];
    const int*   ei   = (const int*)d_in[1];
    const float* W    = (const float*)d_in[2];
    const float* aks  = (const float*)d_in[3];
    const float* akn  = (const float*)d_in[4];
    const float* bias = (const float*)d_in[5];

    const int N  = in_sizes[0] / 128;
    const int E  = in_sizes[1] / 2;
    const int NB = (N + 255) >> 8;
    const int nc = (E + CHUNK - 1) / CHUNK;

    float* out       = (float*)d_out;
    float* alpha_out = out + (size_t)N * 128;
    int2* stage      = (int2*)alpha_out;   // overlays alpha region (see r7 note)

    char* p = (char*)d_ws;
    auto alloc = [&](size_t bytes) {
        char* r = p;
        p += (bytes + 255) & ~(size_t)255;
        return r;
    };
    uint32_t* xpb       = (uint32_t*)alloc((size_t)N * 64 * 4);
    uint32_t* Wp        = (uint32_t*)alloc((size_t)2048 * 16);
    float* attn_self    = (float*)alloc((size_t)N * 4 * 4);
    float* attn_nei     = (float*)alloc((size_t)N * 4 * 4);
    float* inv_arr      = (float*)alloc((size_t)N * 4 * 4);
    int*   offsets      = (int*)alloc((size_t)(N + 1) * 4);
    int*   csr_src      = (int*)alloc((size_t)E * 4);
    int*   bucket_tot   = (int*)alloc((size_t)NB * 4);
    int*   bucket_off   = (int*)alloc((size_t)(NB + 1) * 4);
    int*   start_table  = (int*)alloc((size_t)nc * (NB + 1) * 4);

    hipMemsetAsync(bucket_tot, 0, (size_t)NB * 4, stream);

    w_prep<<<8, 256, 0, stream>>>(W, Wp);
    gemm_xp<<<(N + 63) / 64, 256, 0, stream>>>(x, Wp, aks, akn, xpb,
                                               attn_self, attn_nei, N);
    binA<<<nc, 256, 0, stream>>>(ei, stage, start_table, bucket_tot, NB, E);
    bucket_scan<<<1, 256, 0, stream>>>(bucket_tot, bucket_off, offsets, NB, N, E);
    binB<<<NB, 256, 0, stream>>>(stage, start_table, bucket_off, offsets,
                                 csr_src, nc, NB, N);
    aggregate<<<(N + 3) / 4, 256, 0, stream>>>(csr_src, offsets, xpb,
                                               attn_self, attn_nei, bias, out,
                                               alpha_out, inv_arr, N, E);
    alpha_kernel<<<(E + 255) / 256, 256, 0, stream>>>(ei, attn_self, attn_nei,
                                                      inv_arr, alpha_out, E);
}